// Round 1
// baseline (3963.179 us; speedup 1.0000x reference)
//
#include <hip/hip_runtime.h>

// Problem constants (from reference setup_inputs / NUM_GROUP / GROUP_SIZE)
#define BATCH 32
#define NPTS  8192
#define NGRP  512
#define KNN_K 32

#define FPS_T 1024                 // threads per FPS block
#define PPT   (NPTS / FPS_T)       // 8 points per thread
#define KNN_WPB 4                  // waves (centers) per kNN block

// Exact IEEE (no FMA contraction) squared distance: ((dx*dx + dy*dy) + dz*dz)
__device__ __forceinline__ float sq3(float dx, float dy, float dz) {
    return __fadd_rn(__fadd_rn(__fmul_rn(dx, dx), __fmul_rn(dy, dy)), __fmul_rn(dz, dz));
}

// lexicographic (d, idx) <
__device__ __forceinline__ bool lexlt(float d1, int i1, float d2, int i2) {
    return (d1 < d2) || (d1 == d2 && i1 < i2);
}

// ---------------------------------------------------------------------------
// FPS: one block per batch. Points live in registers (strided n = i*FPS_T+t).
// Per round: distance vs current centroid, min_d update, block argmax
// (first-max-index semantics), owner thread publishes next centroid coords.
// Writes centers [B, G, 3] (exact input values).
// ---------------------------------------------------------------------------
__global__ __launch_bounds__(FPS_T) void fps_kernel(const float* __restrict__ in,
                                                    float* __restrict__ centers) {
    const int b = blockIdx.x;
    const int t = threadIdx.x;
    const float* xp = in + (size_t)b * 3 * NPTS;
    const float* yp = xp + NPTS;
    const float* zp = xp + 2 * NPTS;

    float xr[PPT], yr[PPT], zr[PPT], md[PPT];
#pragma unroll
    for (int i = 0; i < PPT; ++i) {
        int n = i * FPS_T + t;
        xr[i] = xp[n];
        yr[i] = yp[n];
        zr[i] = zp[n];
        md[i] = 1e10f;
    }

    __shared__ float s_cx, s_cy, s_cz;
    __shared__ float s_rv[FPS_T / 64];
    __shared__ int   s_ri[FPS_T / 64];
    __shared__ int   s_cur;

    if (t == 0) {  // farthest starts at index 0, owned by thread 0 (i=0)
        s_cx = xr[0]; s_cy = yr[0]; s_cz = zr[0]; s_cur = 0;
    }
    __syncthreads();

    float* cdst = centers + (size_t)b * NGRP * 3;

    for (int r = 0; r < NGRP; ++r) {
        const float cx = s_cx, cy = s_cy, cz = s_cz;
        if (t == 0) {  // idxs[r] is the PRE-update farthest -> emit its coords
            cdst[r * 3 + 0] = cx;
            cdst[r * 3 + 1] = cy;
            cdst[r * 3 + 2] = cz;
        }

        float bv = -1.0f;
        int   bi = 0x7fffffff;
#pragma unroll
        for (int i = 0; i < PPT; ++i) {
            float d = sq3(__fsub_rn(xr[i], cx), __fsub_rn(yr[i], cy), __fsub_rn(zr[i], cz));
            if (d < md[i]) md[i] = d;
            int n = i * FPS_T + t;
            if (md[i] > bv || (md[i] == bv && n < bi)) { bv = md[i]; bi = n; }
        }
        // wave argmax (ties -> lowest index)
#pragma unroll
        for (int off = 1; off < 64; off <<= 1) {
            float ov = __shfl_xor(bv, off, 64);
            int   oi = __shfl_xor(bi, off, 64);
            if (ov > bv || (ov == bv && oi < bi)) { bv = ov; bi = oi; }
        }
        const int w = t >> 6;
        if ((t & 63) == 0) { s_rv[w] = bv; s_ri[w] = bi; }
        __syncthreads();
        if (t == 0) {
            float fv = s_rv[0];
            int   fi = s_ri[0];
#pragma unroll
            for (int i = 1; i < FPS_T / 64; ++i) {
                float ov = s_rv[i];
                int   oi = s_ri[i];
                if (ov > fv || (ov == fv && oi < fi)) { fv = ov; fi = oi; }
            }
            s_cur = fi;
        }
        __syncthreads();
        const int cur = s_cur;
        if ((cur & (FPS_T - 1)) == t) {  // owner publishes coords for next round
            const int sel = cur / FPS_T;
#pragma unroll
            for (int i = 0; i < PPT; ++i) {
                if (sel == i) { s_cx = xr[i]; s_cy = yr[i]; s_cz = zr[i]; }
            }
        }
        __syncthreads();
    }
}

// ---------------------------------------------------------------------------
// kNN + gather: one wave per center. Each lane scans 128 strided points,
// keeps an exact sorted local top-32 (bulk fill + bitonic, then guarded
// insertion filtered by wave-shared tau_hat >= global 32nd-best). Final
// 32-round wave lex-argmin merge emits neighbors sorted by (d2, idx) --
// identical to stable lax.top_k -- and writes (pt - center).
// ---------------------------------------------------------------------------
__global__ __launch_bounds__(KNN_WPB * 64) void knn_kernel(const float* __restrict__ in,
                                                           const float* __restrict__ centers,
                                                           float* __restrict__ out) {
    const int wave = threadIdx.x >> 6;
    const int lane = threadIdx.x & 63;
    const int cid  = blockIdx.x * KNN_WPB + wave;   // [0, B*G)
    const int b    = cid >> 9;                      // /NGRP

    const float* xp = in + (size_t)b * 3 * NPTS;
    const float* yp = xp + NPTS;
    const float* zp = xp + 2 * NPTS;

    const float cx = centers[cid * 3 + 0];
    const float cy = centers[cid * 3 + 1];
    const float cz = centers[cid * 3 + 2];

    float dist[KNN_K];
    int   idx[KNN_K];

    // Phase A: bulk fill with the first 32 strided points (no compares)
#pragma unroll
    for (int j = 0; j < KNN_K; ++j) {
        int n = j * 64 + lane;
        dist[j] = sq3(__fsub_rn(xp[n], cx), __fsub_rn(yp[n], cy), __fsub_rn(zp[n], cz));
        idx[j]  = n;
    }

    // Phase B: bitonic sort 32 (lexicographic ascending)
#pragma unroll
    for (int k = 2; k <= KNN_K; k <<= 1) {
#pragma unroll
        for (int j = k >> 1; j > 0; j >>= 1) {
#pragma unroll
            for (int i = 0; i < KNN_K; ++i) {
                int l = i ^ j;
                if (l > i) {
                    bool up = ((i & k) == 0);
                    bool sw = up ? lexlt(dist[l], idx[l], dist[i], idx[i])
                                 : lexlt(dist[i], idx[i], dist[l], idx[l]);
                    float td = sw ? dist[l] : dist[i];
                    float ud = sw ? dist[i] : dist[l];
                    int   ti = sw ? idx[l] : idx[i];
                    int   ui = sw ? idx[i] : idx[l];
                    dist[i] = td; dist[l] = ud;
                    idx[i]  = ti; idx[l]  = ui;
                }
            }
        }
    }

    // tau_hat = wave-min of per-lane 32nd best (conservative >= global 32nd)
    float tau = dist[KNN_K - 1];
#pragma unroll
    for (int off = 1; off < 64; off <<= 1) tau = fminf(tau, __shfl_xor(tau, off, 64));

    // Phase C: scan remaining points with guarded insertion
#pragma unroll 1
    for (int j = KNN_K; j < NPTS / 64; ++j) {
        int n = j * 64 + lane;
        float d = sq3(__fsub_rn(xp[n], cx), __fsub_rn(yp[n], cy), __fsub_rn(zp[n], cz));
        if (d <= tau && lexlt(d, n, dist[KNN_K - 1], idx[KNN_K - 1])) {
            dist[KNN_K - 1] = d;
            idx[KNN_K - 1]  = n;
#pragma unroll
            for (int k = KNN_K - 1; k > 0; --k) {
                bool m  = lexlt(dist[k], idx[k], dist[k - 1], idx[k - 1]);
                float da = dist[k - 1], db = dist[k];
                int   ia = idx[k - 1],  ib = idx[k];
                dist[k - 1] = m ? db : da;  dist[k] = m ? da : db;
                idx[k - 1]  = m ? ib : ia;  idx[k]  = m ? ia : ib;
            }
            tau = fminf(tau, dist[KNN_K - 1]);
        }
        if ((j & 15) == 15) {  // periodic wave-wide tau refresh (wave-uniform)
            float tl = dist[KNN_K - 1];
#pragma unroll
            for (int off = 1; off < 64; off <<= 1) tl = fminf(tl, __shfl_xor(tl, off, 64));
            tau = tl;
        }
    }

    // Phase D: 32-round wave lex-argmin merge; winner emits (pt - center)
    const size_t out_base = (size_t)cid * KNN_K * 3;
#pragma unroll 1
    for (int r = 0; r < KNN_K; ++r) {
        float bv = dist[0];
        int   bi = idx[0];
#pragma unroll
        for (int off = 1; off < 64; off <<= 1) {
            float ov = __shfl_xor(bv, off, 64);
            int   oi = __shfl_xor(bi, off, 64);
            if (lexlt(ov, oi, bv, bi)) { bv = ov; bi = oi; }
        }
        bool win = (idx[0] == bi) && (dist[0] == bv);  // idx unique -> 1 winner
        if (win) {
            out[out_base + (size_t)r * 3 + 0] = __fsub_rn(xp[bi], cx);
            out[out_base + (size_t)r * 3 + 1] = __fsub_rn(yp[bi], cy);
            out[out_base + (size_t)r * 3 + 2] = __fsub_rn(zp[bi], cz);
#pragma unroll
            for (int k = 0; k < KNN_K - 1; ++k) { dist[k] = dist[k + 1]; idx[k] = idx[k + 1]; }
            dist[KNN_K - 1] = 1e30f;
            idx[KNN_K - 1]  = 0x7fffffff;
        }
    }
}

extern "C" void kernel_launch(void* const* d_in, const int* in_sizes, int n_in,
                              void* d_out, int out_size, void* d_ws, size_t ws_size,
                              hipStream_t stream) {
    const float* in  = (const float*)d_in[0];
    float* out       = (float*)d_out;
    float* centers   = out + (size_t)BATCH * NGRP * KNN_K * 3;  // second output section

    fps_kernel<<<BATCH, FPS_T, 0, stream>>>(in, centers);
    knn_kernel<<<(BATCH * NGRP) / KNN_WPB, KNN_WPB * 64, 0, stream>>>(in, centers, out);
}

// Round 2
// 1427.569 us; speedup vs baseline: 2.7762x; 2.7762x over previous
//
#include <hip/hip_runtime.h>

typedef unsigned long long u64;
typedef unsigned int u32;

// Problem constants (from reference setup_inputs / NUM_GROUP / GROUP_SIZE)
#define BATCH 32
#define NPTS  8192
#define NGRP  512
#define KNN_K 32

#define FPS_T 1024                 // threads per FPS block
#define PPT   (NPTS / FPS_T)       // 8 points per thread
#define KNN_WPB 4                  // waves (centers) per kNN block

// Exact IEEE (no FMA contraction) squared distance: ((dx*dx + dy*dy) + dz*dz)
__device__ __forceinline__ float sq3(float dx, float dy, float dz) {
    return __fadd_rn(__fadd_rn(__fmul_rn(dx, dx), __fmul_rn(dy, dy)), __fmul_rn(dz, dz));
}

// d >= 0 always (sum of squares) -> IEEE bits are order-monotonic.
// key = (d_bits << 32) | idx  ==> u64 ascending == (d, idx) lexicographic.
__device__ __forceinline__ u64 packdi(float d, int n) {
    return ((u64)__float_as_uint(d) << 32) | (u32)n;
}

__device__ __forceinline__ u64 umin64(u64 a, u64 b) { return a < b ? a : b; }
__device__ __forceinline__ u64 umax64(u64 a, u64 b) { return a > b ? a : b; }

__device__ __forceinline__ u64 shfl_xor_u64(u64 v, int m) {
    int lo = __shfl_xor((int)(u32)v, m, 64);
    int hi = __shfl_xor((int)(u32)(v >> 32), m, 64);
    return ((u64)(u32)hi << 32) | (u32)lo;
}

// ---------------------------------------------------------------------------
// FPS: one block per batch. Points in registers for the distance math, and
// mirrored in LDS so ANY thread can read the winner's coords (broadcast) --
// removes the owner-publish step. Cross-wave argmax via double-buffered
// partials reduced redundantly by all threads. ONE __syncthreads per round.
// argmax key: (md_bits << 32) | ~n  -> u64 MAX == (max d, tie -> lowest n).
// ---------------------------------------------------------------------------
__global__ __launch_bounds__(FPS_T) void fps_kernel(const float* __restrict__ in,
                                                    float* __restrict__ centers) {
    __shared__ float sx[NPTS];
    __shared__ float sy[NPTS];
    __shared__ float sz[NPTS];
    __shared__ u64 s_part[2][FPS_T / 64];

    const int b = blockIdx.x;
    const int t = threadIdx.x;
    const int w = t >> 6;
    const float* xp = in + (size_t)b * 3 * NPTS;
    const float* yp = xp + NPTS;
    const float* zp = xp + 2 * NPTS;

    float xr[PPT], yr[PPT], zr[PPT], md[PPT];
#pragma unroll
    for (int i = 0; i < PPT; ++i) {
        int n = i * FPS_T + t;
        float x = xp[n], y = yp[n], z = zp[n];
        xr[i] = x; yr[i] = y; zr[i] = z;
        sx[n] = x; sy[n] = y; sz[n] = z;
        md[i] = 1e10f;
    }
    __syncthreads();

    float* cdst = centers + (size_t)b * NGRP * 3;
    int cur = 0;

    for (int r = 0; r < NGRP; ++r) {
        const float cx = sx[cur], cy = sy[cur], cz = sz[cur];  // broadcast reads
        if (t == 0) {  // idxs[r] is the PRE-update farthest -> emit its coords
            cdst[r * 3 + 0] = cx;
            cdst[r * 3 + 1] = cy;
            cdst[r * 3 + 2] = cz;
        }

        u64 best = 0;
#pragma unroll
        for (int i = 0; i < PPT; ++i) {
            float d = sq3(__fsub_rn(xr[i], cx), __fsub_rn(yr[i], cy), __fsub_rn(zr[i], cz));
            md[i] = fminf(md[i], d);
            int n = i * FPS_T + t;
            u64 k = ((u64)__float_as_uint(md[i]) << 32) | (u32)(~(u32)n);
            best = umax64(best, k);
        }
#pragma unroll
        for (int off = 1; off < 64; off <<= 1) best = umax64(best, shfl_xor_u64(best, off));
        if ((t & 63) == 0) s_part[r & 1][w] = best;
        __syncthreads();
        u64 m = s_part[r & 1][0];
#pragma unroll
        for (int i = 1; i < FPS_T / 64; ++i) m = umax64(m, s_part[r & 1][i]);
        cur = (int)(~(u32)m);  // recover winning index
    }
}

// ---------------------------------------------------------------------------
// kNN + gather: one wave per center, u64 (dist,idx) keys throughout.
// Phase A: bulk fill 32. Phase B: bitonic sort. Phase C: scan remaining 96
// strided columns with tau-guarded branchless insertion + 1-deep prefetch.
// Phase D: 6-stage XOR butterfly merge (bitonic half-merge + clean, in-place)
// -> every lane ends with the identical global sorted top-32. Output via a
// 1 KB LDS round-trip so lanes 0..31 emit one neighbor each, in rank order
// (== stable lax.top_k order).
// ---------------------------------------------------------------------------
__global__ __launch_bounds__(KNN_WPB * 64) void knn_kernel(const float* __restrict__ in,
                                                           const float* __restrict__ centers,
                                                           float* __restrict__ out) {
    __shared__ u64 s_keys[KNN_WPB][KNN_K];

    const int wave = threadIdx.x >> 6;
    const int lane = threadIdx.x & 63;
    const int cid  = blockIdx.x * KNN_WPB + wave;   // [0, B*G)
    const int b    = cid >> 9;                      // /NGRP

    const float* xp = in + (size_t)b * 3 * NPTS;
    const float* yp = xp + NPTS;
    const float* zp = xp + 2 * NPTS;

    const float cx = centers[cid * 3 + 0];
    const float cy = centers[cid * 3 + 1];
    const float cz = centers[cid * 3 + 2];

    u64 key[KNN_K];

    // Phase A: bulk fill with the first 32 strided columns (no compares)
#pragma unroll
    for (int j = 0; j < KNN_K; ++j) {
        int n = j * 64 + lane;
        float d = sq3(__fsub_rn(xp[n], cx), __fsub_rn(yp[n], cy), __fsub_rn(zp[n], cz));
        key[j] = packdi(d, n);
    }

    // Phase B: bitonic sort 32 ascending
#pragma unroll
    for (int k = 2; k <= KNN_K; k <<= 1) {
#pragma unroll
        for (int j = k >> 1; j > 0; j >>= 1) {
#pragma unroll
            for (int i = 0; i < KNN_K; ++i) {
                int l = i ^ j;
                if (l > i) {
                    bool up = ((i & k) == 0);
                    u64 a = key[i], c = key[l];
                    bool sw = up ? (c < a) : (a < c);
                    key[i] = sw ? c : a;
                    key[l] = sw ? a : c;
                }
            }
        }
    }

    // tau = wave-min of per-lane 32nd best (conservative upper bound on the
    // true global 32nd key; anything > tau can never be in the global top-32)
    u64 tau = key[KNN_K - 1];
#pragma unroll
    for (int off = 1; off < 64; off <<= 1) tau = umin64(tau, shfl_xor_u64(tau, off));

    // Phase C: scan remaining columns, guarded branchless insertion
    float nx = xp[KNN_K * 64 + lane], ny = yp[KNN_K * 64 + lane], nz = zp[KNN_K * 64 + lane];
#pragma unroll 1
    for (int j = KNN_K; j < NPTS / 64; ++j) {
        float x = nx, y = ny, z = nz;
        if (j + 1 < NPTS / 64) {  // 1-deep prefetch for MLP
            int n2 = (j + 1) * 64 + lane;
            nx = xp[n2]; ny = yp[n2]; nz = zp[n2];
        }
        int n = j * 64 + lane;
        float d = sq3(__fsub_rn(x, cx), __fsub_rn(y, cy), __fsub_rn(z, cz));
        u64 kk = packdi(d, n);
        if (kk < tau) {  // tau <= key[31] invariant -> insertion is valid
            key[KNN_K - 1] = kk;
#pragma unroll
            for (int k = KNN_K - 1; k > 0; --k) {
                u64 a = key[k - 1], c = key[k];
                key[k - 1] = umin64(a, c);
                key[k]     = umax64(a, c);
            }
            tau = umin64(tau, key[KNN_K - 1]);
        }
        if ((j & 15) == 15) {  // periodic wave-wide tau refresh
            u64 tl = key[KNN_K - 1];
#pragma unroll
            for (int off = 1; off < 64; off <<= 1) tl = umin64(tl, shfl_xor_u64(tl, off));
            tau = umin64(tau, tl);
        }
    }

    // Phase D: XOR butterfly merge of 64 sorted 32-lists -> global top-32.
    // Per stage: bitonic half-merge against partner (in-place, pairwise
    // j <-> 31-j) then bitonic clean. All shuffles independent within a stage.
#pragma unroll 1
    for (int s = 1; s < 64; s <<= 1) {
#pragma unroll
        for (int j = 0; j < KNN_K / 2; ++j) {
            u64 a = key[j], c = key[KNN_K - 1 - j];
            u64 oa = shfl_xor_u64(a, s);
            u64 oc = shfl_xor_u64(c, s);
            key[j]             = umin64(a, oc);
            key[KNN_K - 1 - j] = umin64(c, oa);
        }
#pragma unroll
        for (int st = KNN_K / 2; st > 0; st >>= 1) {
#pragma unroll
            for (int i = 0; i < KNN_K; ++i) {
                int l = i ^ st;
                if (l > i) {
                    u64 a = key[i], c = key[l];
                    key[i] = umin64(a, c);
                    key[l] = umax64(a, c);
                }
            }
        }
    }

    // All lanes hold the identical global sorted top-32. Lane 0 publishes to
    // LDS; lanes 0..31 each gather + emit one neighbor (rank = lane).
    if (lane == 0) {
#pragma unroll
        for (int j = 0; j < KNN_K; ++j) s_keys[wave][j] = key[j];
    }
    if (lane < KNN_K) {
        u64 kv = s_keys[wave][lane];
        int n = (int)(u32)kv;
        size_t o = (size_t)cid * KNN_K * 3 + (size_t)lane * 3;
        out[o + 0] = __fsub_rn(xp[n], cx);
        out[o + 1] = __fsub_rn(yp[n], cy);
        out[o + 2] = __fsub_rn(zp[n], cz);
    }
}

extern "C" void kernel_launch(void* const* d_in, const int* in_sizes, int n_in,
                              void* d_out, int out_size, void* d_ws, size_t ws_size,
                              hipStream_t stream) {
    const float* in  = (const float*)d_in[0];
    float* out       = (float*)d_out;
    float* centers   = out + (size_t)BATCH * NGRP * KNN_K * 3;  // second output section

    fps_kernel<<<BATCH, FPS_T, 0, stream>>>(in, centers);
    knn_kernel<<<(BATCH * NGRP) / KNN_WPB, KNN_WPB * 64, 0, stream>>>(in, centers, out);
}

// Round 3
// 909.677 us; speedup vs baseline: 4.3567x; 1.5693x over previous
//
#include <hip/hip_runtime.h>

typedef unsigned long long u64;
typedef unsigned int u32;

// Problem constants (from reference setup_inputs / NUM_GROUP / GROUP_SIZE)
#define BATCH 32
#define NPTS  8192
#define NGRP  512
#define KNN_K 32

#define FPS_T 1024                 // threads per FPS block
#define PPT   (NPTS / FPS_T)       // 8 points per thread
#define KNN_WPB 4                  // waves (centers) per kNN block

// Exact IEEE (no FMA contraction) squared distance: ((dx*dx + dy*dy) + dz*dz)
__device__ __forceinline__ float sq3(float dx, float dy, float dz) {
    return __fadd_rn(__fadd_rn(__fmul_rn(dx, dx), __fmul_rn(dy, dy)), __fmul_rn(dz, dz));
}

// d >= 0 always (sum of squares) -> IEEE bits are order-monotonic.
// key = (d_bits << 32) | idx  ==> u64 ascending == (d, idx) lexicographic.
__device__ __forceinline__ u64 packdi(float d, int n) {
    return ((u64)__float_as_uint(d) << 32) | (u32)n;
}

__device__ __forceinline__ u64 umin64(u64 a, u64 b) { return a < b ? a : b; }
__device__ __forceinline__ u64 umax64(u64 a, u64 b) { return a > b ? a : b; }

__device__ __forceinline__ u64 shfl_xor_u64(u64 v, int m) {
    int lo = __shfl_xor((int)(u32)v, m, 64);
    int hi = __shfl_xor((int)(u32)(v >> 32), m, 64);
    return ((u64)(u32)hi << 32) | (u32)lo;
}

__device__ __forceinline__ u64 shfl_u64(u64 v, int src) {
    int lo = __shfl((int)(u32)v, src, 64);
    int hi = __shfl((int)(u32)(v >> 32), src, 64);
    return ((u64)(u32)hi << 32) | (u32)lo;
}

// Cross-lane bitonic sort: one u64 per lane -> ascending by lane index.
__device__ __forceinline__ u64 lane_sort64(u64 v, int lane) {
#pragma unroll
    for (int k = 2; k <= 64; k <<= 1) {
#pragma unroll
        for (int j = k >> 1; j > 0; j >>= 1) {
            u64 p = shfl_xor_u64(v, j);
            // keep min iff (ascending block) == (this is the lower partner)
            bool keepmin = (((lane & k) == 0) == ((lane & j) == 0));
            u64 mn = umin64(v, p), mx = umax64(v, p);
            v = keepmin ? mn : mx;
        }
    }
    return v;
}

// m, c both ascending-sorted across lanes; returns the lowest 64 of the 128,
// ascending-sorted. (reverse c, elementwise min -> bitonic, 6-level clean)
__device__ __forceinline__ u64 lane_merge64(u64 m, u64 c, int lane) {
    u64 cr = shfl_xor_u64(c, 63);  // lane ^ 63 == 63 - lane (reverse)
    u64 z = umin64(m, cr);
#pragma unroll
    for (int dd = 32; dd > 0; dd >>= 1) {
        u64 p = shfl_xor_u64(z, dd);
        u64 mn = umin64(z, p), mx = umax64(z, p);
        z = (lane & dd) ? mx : mn;
    }
    return z;
}

// ---------------------------------------------------------------------------
// FPS: one block per batch. Points in registers for the distance math and
// mirrored in LDS for winner-coordinate broadcast. One barrier per round.
// Inner loop tracks (best_d, best_n) with a float compare (tie -> lowest n,
// since n is ascending within a thread); key packed once per round.
// Final cross-wave reduce: lane-parallel 4-level shuffle over 16 partials.
// ---------------------------------------------------------------------------
__global__ __launch_bounds__(FPS_T) void fps_kernel(const float* __restrict__ in,
                                                    float* __restrict__ centers) {
    __shared__ float sx[NPTS];
    __shared__ float sy[NPTS];
    __shared__ float sz[NPTS];
    __shared__ u64 s_part[2][FPS_T / 64];

    const int b = blockIdx.x;
    const int t = threadIdx.x;
    const int w = t >> 6;
    const float* xp = in + (size_t)b * 3 * NPTS;
    const float* yp = xp + NPTS;
    const float* zp = xp + 2 * NPTS;

    float xr[PPT], yr[PPT], zr[PPT], md[PPT];
#pragma unroll
    for (int i = 0; i < PPT; ++i) {
        int n = i * FPS_T + t;
        float x = xp[n], y = yp[n], z = zp[n];
        xr[i] = x; yr[i] = y; zr[i] = z;
        sx[n] = x; sy[n] = y; sz[n] = z;
        md[i] = 1e10f;
    }
    __syncthreads();

    float* cdst = centers + (size_t)b * NGRP * 3;
    int cur = 0;

    for (int r = 0; r < NGRP; ++r) {
        const float cx = sx[cur], cy = sy[cur], cz = sz[cur];  // broadcast reads
        if (t == 0) {  // idxs[r] is the PRE-update farthest -> emit its coords
            cdst[r * 3 + 0] = cx;
            cdst[r * 3 + 1] = cy;
            cdst[r * 3 + 2] = cz;
        }

        float bd = -1.0f;
        int   bi = 0;
#pragma unroll
        for (int i = 0; i < PPT; ++i) {
            float d = sq3(__fsub_rn(xr[i], cx), __fsub_rn(yr[i], cy), __fsub_rn(zr[i], cz));
            md[i] = fminf(md[i], d);
            if (md[i] > bd) { bd = md[i]; bi = i * FPS_T + t; }  // strict > : first max
        }
        // pack key: max (d, tie -> lowest n) == u64 max of (d_bits, ~n)
        u64 best = ((u64)__float_as_uint(bd) << 32) | (u32)(~(u32)bi);
#pragma unroll
        for (int off = 1; off < 64; off <<= 1) best = umax64(best, shfl_xor_u64(best, off));
        if ((t & 63) == 0) s_part[r & 1][w] = best;
        __syncthreads();
        // lane-parallel reduce of 16 partials (4 shuffle levels, all lanes)
        u64 p = s_part[r & 1][t & 15];
#pragma unroll
        for (int off = 1; off < 16; off <<= 1) p = umax64(p, shfl_xor_u64(p, off));
        cur = (int)(~(u32)p);  // recover winning index
    }
}

// ---------------------------------------------------------------------------
// kNN + gather: one wave per center. Wave-cooperative exact top-32:
// reg m = sorted-64 across lanes (lanes 0..31 hold the exact running top-32
// of the prefix; keys dropped past position 63 provably have >=64 smaller
// keys, so they can never be top-32). tau = m[31] = running exact 32nd.
// Per column: dist, pack, tau-filter, 1-deep per-lane enqueue. On slot
// collision (ballot): flush = cross-lane sort-64 of queue + bitonic merge.
// Output: lane i < 32 holds the i-th neighbor (ascending (d,idx) == stable
// lax.top_k order); direct coalesced-ish store, no LDS anywhere.
// ---------------------------------------------------------------------------
__global__ __launch_bounds__(KNN_WPB * 64) void knn_kernel(const float* __restrict__ in,
                                                           const float* __restrict__ centers,
                                                           float* __restrict__ out) {
    const int wave = threadIdx.x >> 6;
    const int lane = threadIdx.x & 63;
    const int cid  = blockIdx.x * KNN_WPB + wave;   // [0, B*G)
    const int b    = cid >> 9;                      // /NGRP

    const float* xp = in + (size_t)b * 3 * NPTS;
    const float* yp = xp + NPTS;
    const float* zp = xp + 2 * NPTS;

    const float cx = centers[cid * 3 + 0];
    const float cy = centers[cid * 3 + 1];
    const float cz = centers[cid * 3 + 2];

    // seed: column 0 (points 0..63), exact sorted top-64
    float x = xp[lane], y = yp[lane], z = zp[lane];
    u64 m = packdi(sq3(__fsub_rn(x, cx), __fsub_rn(y, cy), __fsub_rn(z, cz)), lane);
    m = lane_sort64(m, lane);
    u64 tau = shfl_u64(m, 31);
    u64 q = ~0ull;  // empty pending slot

    float nx = xp[64 + lane], ny = yp[64 + lane], nz = zp[64 + lane];
#pragma unroll 1
    for (int j = 1; j < NPTS / 64; ++j) {
        x = nx; y = ny; z = nz;
        if (j + 1 < NPTS / 64) {  // 1-deep prefetch
            int n2 = (j + 1) * 64 + lane;
            nx = xp[n2]; ny = yp[n2]; nz = zp[n2];
        }
        float d = sq3(__fsub_rn(x, cx), __fsub_rn(y, cy), __fsub_rn(z, cz));
        u64 kk = packdi(d, j * 64 + lane);
        bool cand = kk < tau;  // strict: kk == tau is already in m
        if (__ballot(cand && (q != ~0ull))) {  // someone needs a free slot
            u64 c = lane_sort64(q, lane);
            m = lane_merge64(m, c, lane);
            tau = shfl_u64(m, 31);   // tau only decreases; stale cand harmless
            q = ~0ull;
        }
        if (cand) q = kk;
    }
    if (__ballot(q != ~0ull)) {  // drain
        u64 c = lane_sort64(q, lane);
        m = lane_merge64(m, c, lane);
    }

    if (lane < KNN_K) {
        int n = (int)(u32)m;
        size_t o = (size_t)cid * (KNN_K * 3) + (size_t)lane * 3;
        out[o + 0] = __fsub_rn(xp[n], cx);
        out[o + 1] = __fsub_rn(yp[n], cy);
        out[o + 2] = __fsub_rn(zp[n], cz);
    }
}

extern "C" void kernel_launch(void* const* d_in, const int* in_sizes, int n_in,
                              void* d_out, int out_size, void* d_ws, size_t ws_size,
                              hipStream_t stream) {
    const float* in  = (const float*)d_in[0];
    float* out       = (float*)d_out;
    float* centers   = out + (size_t)BATCH * NGRP * KNN_K * 3;  // second output section

    fps_kernel<<<BATCH, FPS_T, 0, stream>>>(in, centers);
    knn_kernel<<<(BATCH * NGRP) / KNN_WPB, KNN_WPB * 64, 0, stream>>>(in, centers, out);
}

// Round 4
// 694.896 us; speedup vs baseline: 5.7033x; 1.3091x over previous
//
#include <hip/hip_runtime.h>

typedef unsigned long long u64;
typedef unsigned int u32;
typedef float v2f __attribute__((ext_vector_type(2)));

// Problem constants (from reference setup_inputs / NUM_GROUP / GROUP_SIZE)
#define BATCH 32
#define NPTS  8192
#define NGRP  512
#define KNN_K 32

#define FPS_T 256                  // threads per FPS block (4 waves)
#define PPAIR (NPTS / FPS_T / 2)   // 16 point-PAIRS per thread
#define KNN_WPB 4                  // waves (centers) per kNN block

// Exact IEEE (no FMA contraction) squared distance: ((dx*dx + dy*dy) + dz*dz)
__device__ __forceinline__ float sq3(float dx, float dy, float dz) {
    return __fadd_rn(__fadd_rn(__fmul_rn(dx, dx), __fmul_rn(dy, dy)), __fmul_rn(dz, dz));
}

// d >= 0 always (sum of squares) -> IEEE bits are order-monotonic.
// key = (d_bits << 32) | idx  ==> u64 ascending == (d, idx) lexicographic.
__device__ __forceinline__ u64 packdi(float d, int n) {
    return ((u64)__float_as_uint(d) << 32) | (u32)n;
}

__device__ __forceinline__ u64 umin64(u64 a, u64 b) { return a < b ? a : b; }
__device__ __forceinline__ u64 umax64(u64 a, u64 b) { return a > b ? a : b; }

__device__ __forceinline__ u64 shfl_xor_u64(u64 v, int m) {
    int lo = __shfl_xor((int)(u32)v, m, 64);
    int hi = __shfl_xor((int)(u32)(v >> 32), m, 64);
    return ((u64)(u32)hi << 32) | (u32)lo;
}

__device__ __forceinline__ u64 shfl_u64(u64 v, int src) {
    int lo = __shfl((int)(u32)v, src, 64);
    int hi = __shfl((int)(u32)(v >> 32), src, 64);
    return ((u64)(u32)hi << 32) | (u32)lo;
}

// ---- DPP wave-64 u64-max reduction (result valid in lane 63) --------------
// update_dpp(old=0, bound_ctrl=1): lanes with invalid DPP source read 0.
// 0 is a safe identity: every real key has low32 = ~n >= 0xFFFFE000 > 0.
template <int CTRL>
__device__ __forceinline__ u64 dpp_max_step(u64 k) {
    u32 plo = (u32)__builtin_amdgcn_update_dpp(0, (int)(u32)k, CTRL, 0xF, 0xF, true);
    u32 phi = (u32)__builtin_amdgcn_update_dpp(0, (int)(u32)(k >> 32), CTRL, 0xF, 0xF, true);
    u64 p = ((u64)phi << 32) | plo;
    return k > p ? k : p;
}
__device__ __forceinline__ u64 dpp_wave_max(u64 k) {
    k = dpp_max_step<0x111>(k);  // row_shr:1
    k = dpp_max_step<0x112>(k);  // row_shr:2
    k = dpp_max_step<0x114>(k);  // row_shr:4
    k = dpp_max_step<0x118>(k);  // row_shr:8   -> lanes 15/31/47/63 = row max
    k = dpp_max_step<0x142>(k);  // row_bcast15 -> lane31 = rows0-1, lane63 = rows2-3
    k = dpp_max_step<0x143>(k);  // row_bcast31 -> lane63 = full wave
    return k;
}

// Cross-lane bitonic sort: one u64 per lane -> ascending by lane index.
__device__ __forceinline__ u64 lane_sort64(u64 v, int lane) {
#pragma unroll
    for (int k = 2; k <= 64; k <<= 1) {
#pragma unroll
        for (int j = k >> 1; j > 0; j >>= 1) {
            u64 p = shfl_xor_u64(v, j);
            bool keepmin = (((lane & k) == 0) == ((lane & j) == 0));
            u64 mn = umin64(v, p), mx = umax64(v, p);
            v = keepmin ? mn : mx;
        }
    }
    return v;
}

// m, c both ascending-sorted across lanes; returns the lowest 64 of the 128,
// ascending-sorted. (reverse c, elementwise min -> bitonic, 6-level clean)
__device__ __forceinline__ u64 lane_merge64(u64 m, u64 c, int lane) {
    u64 cr = shfl_xor_u64(c, 63);
    u64 z = umin64(m, cr);
#pragma unroll
    for (int dd = 32; dd > 0; dd >>= 1) {
        u64 p = shfl_xor_u64(z, dd);
        u64 mn = umin64(z, p), mx = umax64(z, p);
        z = (lane & dd) ? mx : mn;
    }
    return z;
}

// ---------------------------------------------------------------------------
// FPS: one block per batch, 256 threads, 32 points/thread held as 16 float2
// pairs (v_pk_* packed fp32; contract(off) keeps per-op IEEE rounding ==
// numpy). LDS mirror only for the once-per-round winner-coordinate lookup.
// Per round: pk distance+min update, two first-max chains (even/odd n),
// u64 (d,~n) pack, 6-step DPP wave argmax (lane 63), lane-63 LDS write,
// barrier, 4-partial broadcast merge. One barrier per round.
// ---------------------------------------------------------------------------
__global__ __launch_bounds__(FPS_T) void fps_kernel(const float* __restrict__ in,
                                                    float* __restrict__ centers) {
#pragma clang fp contract(off)
    __shared__ float sx[NPTS];
    __shared__ float sy[NPTS];
    __shared__ float sz[NPTS];
    __shared__ u64 s_key[2][FPS_T / 64];

    const int b = blockIdx.x;
    const int t = threadIdx.x;
    const int w = t >> 6;
    const float* xp = in + (size_t)b * 3 * NPTS;
    const float* yp = xp + NPTS;
    const float* zp = xp + 2 * NPTS;

    v2f xr[PPAIR], yr[PPAIR], zr[PPAIR], md[PPAIR];
#pragma unroll
    for (int i = 0; i < PPAIR; ++i) {
        int n = i * (2 * FPS_T) + 2 * t;       // pair covers points n, n+1
        xr[i] = *(const v2f*)(xp + n);
        yr[i] = *(const v2f*)(yp + n);
        zr[i] = *(const v2f*)(zp + n);
        *(v2f*)(sx + n) = xr[i];
        *(v2f*)(sy + n) = yr[i];
        *(v2f*)(sz + n) = zr[i];
        md[i] = (v2f){1e10f, 1e10f};
    }
    __syncthreads();

    float* cdst = centers + (size_t)b * NGRP * 3;
    int cur = 0;

    for (int r = 0; r < NGRP; ++r) {
        const float cx = sx[cur], cy = sy[cur], cz = sz[cur];  // broadcast reads
        if (t == 0) {  // idxs[r] is the PRE-update farthest -> emit its coords
            cdst[r * 3 + 0] = cx;
            cdst[r * 3 + 1] = cy;
            cdst[r * 3 + 2] = cz;
        }

        float bd0 = -1.0f, bd1 = -1.0f;
        int   bi0 = 0,     bi1 = 0;
#pragma unroll
        for (int i = 0; i < PPAIR; ++i) {
            v2f dx = xr[i] - cx;
            v2f dy = yr[i] - cy;
            v2f dz = zr[i] - cz;
            v2f dd = dx * dx + dy * dy + dz * dz;  // contract(off): 3 mul + 2 add
            md[i] = __builtin_elementwise_min(md[i], dd);
            int n = i * (2 * FPS_T) + 2 * t;
            if (md[i].x > bd0) { bd0 = md[i].x; bi0 = n; }      // strict >: first max
            if (md[i].y > bd1) { bd1 = md[i].y; bi1 = n + 1; }
        }
        // max (d, tie -> lowest n) == u64 max of (d_bits, ~n)
        u64 k0 = ((u64)__float_as_uint(bd0) << 32) | (u32)(~(u32)bi0);
        u64 k1 = ((u64)__float_as_uint(bd1) << 32) | (u32)(~(u32)bi1);
        u64 k = dpp_wave_max(umax64(k0, k1));
        if ((t & 63) == 63) s_key[r & 1][w] = k;  // lane 63 holds the wave winner
        __syncthreads();
        u64 m = umax64(umax64(s_key[r & 1][0], s_key[r & 1][1]),
                       umax64(s_key[r & 1][2], s_key[r & 1][3]));
        cur = (int)(~(u32)m);  // recover winning index
    }
}

// ---------------------------------------------------------------------------
// kNN + gather: one wave per center. Wave-cooperative exact top-32 (see R2/R3
// notes): sorted-64 register list across lanes, tau = exact running 32nd,
// 1-deep per-lane pending queue, ballot-triggered sort+merge flush.
// ---------------------------------------------------------------------------
__global__ __launch_bounds__(KNN_WPB * 64) void knn_kernel(const float* __restrict__ in,
                                                           const float* __restrict__ centers,
                                                           float* __restrict__ out) {
    const int wave = threadIdx.x >> 6;
    const int lane = threadIdx.x & 63;
    const int cid  = blockIdx.x * KNN_WPB + wave;   // [0, B*G)
    const int b    = cid >> 9;                      // /NGRP

    const float* xp = in + (size_t)b * 3 * NPTS;
    const float* yp = xp + NPTS;
    const float* zp = xp + 2 * NPTS;

    const float cx = centers[cid * 3 + 0];
    const float cy = centers[cid * 3 + 1];
    const float cz = centers[cid * 3 + 2];

    // seed: column 0 (points 0..63), exact sorted top-64
    float x = xp[lane], y = yp[lane], z = zp[lane];
    u64 m = packdi(sq3(__fsub_rn(x, cx), __fsub_rn(y, cy), __fsub_rn(z, cz)), lane);
    m = lane_sort64(m, lane);
    u64 tau = shfl_u64(m, 31);
    u64 q = ~0ull;  // empty pending slot

    float nx = xp[64 + lane], ny = yp[64 + lane], nz = zp[64 + lane];
#pragma unroll 1
    for (int j = 1; j < NPTS / 64; ++j) {
        x = nx; y = ny; z = nz;
        if (j + 1 < NPTS / 64) {  // 1-deep prefetch
            int n2 = (j + 1) * 64 + lane;
            nx = xp[n2]; ny = yp[n2]; nz = zp[n2];
        }
        float d = sq3(__fsub_rn(x, cx), __fsub_rn(y, cy), __fsub_rn(z, cz));
        u64 kk = packdi(d, j * 64 + lane);
        bool cand = kk < tau;  // strict: kk == tau is already in m
        if (__ballot(cand && (q != ~0ull))) {  // someone needs a free slot
            u64 c = lane_sort64(q, lane);
            m = lane_merge64(m, c, lane);
            tau = shfl_u64(m, 31);   // tau only decreases; stale cand harmless
            q = ~0ull;
        }
        if (cand) q = kk;
    }
    if (__ballot(q != ~0ull)) {  // drain
        u64 c = lane_sort64(q, lane);
        m = lane_merge64(m, c, lane);
    }

    if (lane < KNN_K) {
        int n = (int)(u32)m;
        size_t o = (size_t)cid * (KNN_K * 3) + (size_t)lane * 3;
        out[o + 0] = __fsub_rn(xp[n], cx);
        out[o + 1] = __fsub_rn(yp[n], cy);
        out[o + 2] = __fsub_rn(zp[n], cz);
    }
}

extern "C" void kernel_launch(void* const* d_in, const int* in_sizes, int n_in,
                              void* d_out, int out_size, void* d_ws, size_t ws_size,
                              hipStream_t stream) {
    const float* in  = (const float*)d_in[0];
    float* out       = (float*)d_out;
    float* centers   = out + (size_t)BATCH * NGRP * KNN_K * 3;  // second output section

    fps_kernel<<<BATCH, FPS_T, 0, stream>>>(in, centers);
    knn_kernel<<<(BATCH * NGRP) / KNN_WPB, KNN_WPB * 64, 0, stream>>>(in, centers, out);
}